// Round 10
// baseline (20067.131 us; speedup 1.0000x reference)
//
#include <hip/hip_runtime.h>
#include <hip/hip_bf16.h>

#define T_STEPS 2048
#define NN 4000
#define N_IN 32
#define N_OUT 32
#define NEXT 4032          // N_IN + NN
#define NWG 250            // workgroups in persistent scan kernel
#define ROWS_PER_WG 16     // 250*16 = 4000
#define TPB 256
#define MAX_NNZ 7680       // per-WG LDS nnz capacity (mean 6400, sigma 76)
#define LEAK 0.99f

// ---------------------------------------------------------------------------
// drive[t][n] = b + sum_k X[t][k]*W_in[n][k] + sum_k y[t][k]*W_fb[n][k]
// ---------------------------------------------------------------------------
__global__ void drive_kernel(const float* __restrict__ X, const float* __restrict__ y,
                             const float* __restrict__ W_in, const float* __restrict__ W_fb,
                             const float* __restrict__ b, float* __restrict__ drive) {
  __shared__ float s_x[N_IN];
  __shared__ float s_y[N_OUT];
  const int t = blockIdx.y;
  const int tid = threadIdx.x;
  if (tid < N_IN) s_x[tid] = X[t * N_IN + tid];
  else if (tid < N_IN + N_OUT) s_y[tid - N_IN] = y[t * N_OUT + (tid - N_IN)];
  __syncthreads();
  const int n = blockIdx.x * TPB + tid;
  if (n < NN) {
    float acc = b[0];
    const float* wi = W_in + (size_t)n * N_IN;
    const float* wf = W_fb + (size_t)n * N_OUT;
#pragma unroll
    for (int k = 0; k < N_IN; ++k) acc += s_x[k] * wi[k];
#pragma unroll
    for (int k = 0; k < N_OUT; ++k) acc += s_y[k] * wf[k];
    drive[(size_t)t * NN + n] = acc;
  }
}

// ---------------------------------------------------------------------------
__global__ void transpose_wout_kernel(const float* __restrict__ W_out, float* __restrict__ WoT) {
  const int idx = blockIdx.x * TPB + threadIdx.x;
  if (idx < N_OUT * NEXT) {
    const int o = idx / NEXT;
    const int k = idx % NEXT;
    WoT[k * N_OUT + o] = W_out[idx];
  }
}

// ---------------------------------------------------------------------------
// Persistent scan kernel. 250 WGs x 256 threads, 1 WG/CU.
// CSR slice of 16 rows packed {val,col} in LDS.
// SELF-FLAGGING DATA exchange (no fences, no vmcnt drain, no tags):
//   producer row stores ONE b64 packed word {tag=t+1 (hi), h bits (lo)} into
//   pdata[t&1][row] (relaxed agent WT). Consumers poll their producer's 16
//   packed words; tag arrival == data arrival (one one-way flight).
// Skew safety of 2 parity buffers: producer p can overwrite parity slot
// (step t+2) only after passing step t+1's poll, which needs every WG's t+1
// publish, which needs their step-t pull complete. Max skew 1 step. QED.
// Own-WG rows short-circuit via LDS (no IF round trip).
// ---------------------------------------------------------------------------
__global__ __launch_bounds__(TPB, 1) void esn_scan_kernel(
    const float* __restrict__ W_res,
    const float* __restrict__ drive,
    float* __restrict__ states,
    unsigned long long* __restrict__ pdata) {  // [2][NN] packed {tag,h}
  __shared__ float2 s_pk[MAX_NNZ];          // {val, col bits} : one b64 per nnz
  __shared__ __align__(16) float s_h[NN];
  __shared__ unsigned s_cnt[ROWS_PER_WG];
  __shared__ unsigned s_start[ROWS_PER_WG + 1];

  const int tid = threadIdx.x;
  const int wg = blockIdx.x;
  const int row0 = wg * ROWS_PER_WG;
  const int wave = tid >> 6;
  const int lane = tid & 63;

  // ---- pass 1: count nonzeros per row ----
  for (int rl = 0; rl < 4; ++rl) {
    const int r = wave * 4 + rl;
    const float* wrow = W_res + (size_t)(row0 + r) * NN;
    unsigned cnt = 0;
    for (int c0 = 0; c0 < NN; c0 += 64) {
      const int c = c0 + lane;
      const float w = (c < NN) ? wrow[c] : 0.0f;
      cnt += (unsigned)__popcll(__ballot(w != 0.0f));
    }
    if (lane == 0) s_cnt[r] = cnt;
  }
  __syncthreads();
  if (tid == 0) {
    unsigned acc = 0;
    for (int r = 0; r < ROWS_PER_WG; ++r) { s_start[r] = acc; acc += s_cnt[r]; }
    s_start[ROWS_PER_WG] = acc;
  }
  __syncthreads();

  // ---- pass 2: ordered fill, packed {val, col} ----
  for (int rl = 0; rl < 4; ++rl) {
    const int r = wave * 4 + rl;
    const float* wrow = W_res + (size_t)(row0 + r) * NN;
    unsigned off = s_start[r];
    for (int c0 = 0; c0 < NN; c0 += 64) {
      const int c = c0 + lane;
      const float w = (c < NN) ? wrow[c] : 0.0f;
      const unsigned long long m = __ballot(w != 0.0f);
      if (w != 0.0f) {
        const unsigned pos = off + (unsigned)__popcll(m & ((1ULL << lane) - 1ULL));
        if (pos < MAX_NNZ) s_pk[pos] = make_float2(w, __uint_as_float((unsigned)c));
      }
      off += (unsigned)__popcll(m);
    }
  }

  for (int i = tid; i < NN; i += TPB) s_h[i] = 0.0f;   // h_0 = 0
  __syncthreads();

  const int r = tid >> 4;       // row within slice (0..15)
  const int l16 = tid & 15;     // lane within row-group
  const int myrow = row0 + r;
  const unsigned kbeg = s_start[r];
  const unsigned kend = s_start[r + 1];

  // fused poll+pull assignment: thread tid handles producer p (p==wg skipped:
  // own rows arrive via LDS short-circuit)
  const int p = (tid < NWG) ? (tid + wg) % NWG : 0;
  const int jrot = tid & 15;    // rotation to spread LDS write banks

  float dv = (l16 == 0) ? drive[myrow] : 0.0f;   // drive for t=0

  for (int t = 0; t < T_STEPS; ++t) {
    // ---- gather: 2-way unrolled, 2 LDS instrs per nnz ----
    float acc0 = 0.0f, acc1 = 0.0f;
    unsigned k = kbeg + (unsigned)l16;
    for (; k + 16 < kend; k += 32) {
      const float2 p0 = s_pk[k];
      const float2 p1 = s_pk[k + 16];
      acc0 += p0.x * s_h[__float_as_uint(p0.y)];
      acc1 += p1.x * s_h[__float_as_uint(p1.y)];
    }
    if (k < kend) { const float2 pk = s_pk[k]; acc0 += pk.x * s_h[__float_as_uint(pk.y)]; }
    float acc = acc0 + acc1;
    acc += __shfl_xor(acc, 1);
    acc += __shfl_xor(acc, 2);
    acc += __shfl_xor(acc, 4);
    acc += __shfl_xor(acc, 8);

    // prefetch next step's drive (1 cacheline per WG) to hide latency
    const float dv_next = (l16 == 0 && t + 1 < T_STEPS)
                              ? drive[(size_t)(t + 1) * NN + myrow] : 0.0f;

    const unsigned tgt = (unsigned)(t + 1);
    float hn = 0.0f;
    if (l16 == 0) {
      hn = LEAK * tanhf(acc + dv) + (1.0f - LEAK) * s_h[myrow];
      // self-flagging publish: ONE b64 WT agent store {tag, h}
      const unsigned long long pk =
          ((unsigned long long)tgt << 32) | (unsigned long long)__float_as_uint(hn);
      __hip_atomic_store(&pdata[(size_t)(t & 1) * NN + myrow], pk,
                         __ATOMIC_RELAXED, __HIP_MEMORY_SCOPE_AGENT);
      // plain WT store for out_kernel (never polled)
      __hip_atomic_store(&states[(size_t)t * NN + myrow], hn,
                         __ATOMIC_RELAXED, __HIP_MEMORY_SCOPE_AGENT);
    }
    dv = dv_next;
    if (t == T_STEPS - 1) break;

    __syncthreads();     // B1: all gathers done — s_h free to overwrite

    if (l16 == 0) s_h[myrow] = hn;   // own rows: LDS short-circuit

    if (tid < NWG && p != wg) {
      const unsigned long long* src = pdata + (size_t)(t & 1) * NN + (size_t)p * 16;
      unsigned long long v[16];
      for (;;) {
        bool ok = true;
#pragma unroll
        for (int j = 0; j < 16; ++j) {
          v[j] = __hip_atomic_load(&src[j], __ATOMIC_RELAXED,
                                   __HIP_MEMORY_SCOPE_AGENT);
          ok &= ((unsigned)(v[j] >> 32) >= tgt);
        }
        if (ok) break;
        __builtin_amdgcn_s_sleep(1);
      }
#pragma unroll
      for (int jj = 0; jj < 16; ++jj) {
        const int j = (jj + jrot) & 15;
        s_h[p * 16 + j] = __uint_as_float((unsigned)v[j]);
      }
    }
    __syncthreads();     // B2: s_h = h_{t+1} complete
  }
}

// ---------------------------------------------------------------------------
__global__ void out_kernel(const float* __restrict__ X, const float* __restrict__ states,
                           const float* __restrict__ WoT, float* __restrict__ out) {
  const int o = threadIdx.x & 31;
  const int tl = threadIdx.x >> 5;
  const int t = blockIdx.x * 8 + tl;
  float acc = 0.0f;
  const float* xrow = X + (size_t)t * N_IN;
#pragma unroll
  for (int k = 0; k < N_IN; ++k) acc += xrow[k] * WoT[k * N_OUT + o];
  const float* srow = states + (size_t)t * NN;
  for (int j = 0; j < NN; ++j) acc += srow[j] * WoT[(N_IN + j) * N_OUT + o];
  out[(size_t)t * N_OUT + o] = acc;
}

// ---------------------------------------------------------------------------
extern "C" void kernel_launch(void* const* d_in, const int* in_sizes, int n_in,
                              void* d_out, int out_size, void* d_ws, size_t ws_size,
                              hipStream_t stream) {
  const float* X     = (const float*)d_in[0];
  const float* y     = (const float*)d_in[1];
  const float* W_in  = (const float*)d_in[2];
  const float* W_res = (const float*)d_in[3];
  const float* W_fb  = (const float*)d_in[4];
  const float* W_out = (const float*)d_in[5];
  const float* b     = (const float*)d_in[6];
  float* out = (float*)d_out;

  // workspace layout (float offsets):
  //   drive : [2048][4000]        at 0            (8,192,000)
  //   states: [2048][4000]        at 8,192,000    (8,192,000)
  //   WoT   : [4032][32]          at 16,384,000   (129,024)
  //   pdata : [2][4000] u64       at 16,513,024   (16,000 floats; 8B-aligned)
  float* ws = (float*)d_ws;
  float* drive    = ws;
  float* states   = ws + 8192000;
  float* WoT      = ws + 16384000;
  unsigned long long* pdata = (unsigned long long*)(ws + 16513024);

  hipMemsetAsync(pdata, 0, 2 * NN * sizeof(unsigned long long), stream);
  drive_kernel<<<dim3(16, T_STEPS), TPB, 0, stream>>>(X, y, W_in, W_fb, b, drive);
  transpose_wout_kernel<<<(N_OUT * NEXT + TPB - 1) / TPB, TPB, 0, stream>>>(W_out, WoT);
  esn_scan_kernel<<<NWG, TPB, 0, stream>>>(W_res, drive, states, pdata);
  out_kernel<<<T_STEPS / 8, TPB, 0, stream>>>(X, states, WoT, out);
}

// Round 11
// 16180.687 us; speedup vs baseline: 1.2402x; 1.2402x over previous
//
#include <hip/hip_runtime.h>
#include <hip/hip_bf16.h>

#define T_STEPS 2048
#define NN 4000
#define N_IN 32
#define N_OUT 32
#define NEXT 4032          // N_IN + NN
#define NWG 250            // workgroups in persistent scan kernel
#define ROWS_PER_WG 16     // 250*16 = 4000
#define TPB 256
#define MAX_NNZ 7680       // per-WG LDS nnz capacity (mean 6400, sigma 76)
#define LEAK 0.99f

// ---------------------------------------------------------------------------
// drive[t][n] = b + sum_k X[t][k]*W_in[n][k] + sum_k y[t][k]*W_fb[n][k]
// ---------------------------------------------------------------------------
__global__ void drive_kernel(const float* __restrict__ X, const float* __restrict__ y,
                             const float* __restrict__ W_in, const float* __restrict__ W_fb,
                             const float* __restrict__ b, float* __restrict__ drive) {
  __shared__ float s_x[N_IN];
  __shared__ float s_y[N_OUT];
  const int t = blockIdx.y;
  const int tid = threadIdx.x;
  if (tid < N_IN) s_x[tid] = X[t * N_IN + tid];
  else if (tid < N_IN + N_OUT) s_y[tid - N_IN] = y[t * N_OUT + (tid - N_IN)];
  __syncthreads();
  const int n = blockIdx.x * TPB + tid;
  if (n < NN) {
    float acc = b[0];
    const float* wi = W_in + (size_t)n * N_IN;
    const float* wf = W_fb + (size_t)n * N_OUT;
#pragma unroll
    for (int k = 0; k < N_IN; ++k) acc += s_x[k] * wi[k];
#pragma unroll
    for (int k = 0; k < N_OUT; ++k) acc += s_y[k] * wf[k];
    drive[(size_t)t * NN + n] = acc;
  }
}

// ---------------------------------------------------------------------------
__global__ void transpose_wout_kernel(const float* __restrict__ W_out, float* __restrict__ WoT) {
  const int idx = blockIdx.x * TPB + threadIdx.x;
  if (idx < N_OUT * NEXT) {
    const int o = idx / NEXT;
    const int k = idx % NEXT;
    WoT[k * N_OUT + o] = W_out[idx];
  }
}

// ---------------------------------------------------------------------------
// Persistent scan kernel. 250 WGs x 256 threads, 1 WG/CU.
// CSR slice of 16 rows packed {val,col} in LDS.
// SELF-FLAGGING v2 exchange (no fences, no vmcnt ack, no tag leg):
//   producers: ONE b64 WT agent store per row into pdata[t&1] = {tag, h}.
//   consumers: spin on ONE word (index 15) of their producer's chunk —
//     poll volume == R9's tag level (known-good). When it carries tag>=t+1,
//     burst-load the other 15 words and validate embedded tags (issued
//     back-to-back by producer => first burst almost always passes).
// Parity-2 safety: producer overwrites pdata[t&1] at step t+2 only after
// passing its step-t+1 pull, which needs every WG's t+1 publish, which needs
// their step-t pull complete. Max skew 1 step.
// Own-WG rows short-circuit via LDS. states[] kept as plain cached stores
// (only out_kernel reads it, after kernel end).
// ---------------------------------------------------------------------------
__global__ __launch_bounds__(TPB, 1) void esn_scan_kernel(
    const float* __restrict__ W_res,
    const float* __restrict__ drive,
    float* __restrict__ states,
    unsigned long long* __restrict__ pdata) {  // [2][NN] packed {tag,h}
  __shared__ float2 s_pk[MAX_NNZ];          // {val, col bits} : one b64 per nnz
  __shared__ __align__(16) float s_h[NN];
  __shared__ unsigned s_cnt[ROWS_PER_WG];
  __shared__ unsigned s_start[ROWS_PER_WG + 1];

  const int tid = threadIdx.x;
  const int wg = blockIdx.x;
  const int row0 = wg * ROWS_PER_WG;
  const int wave = tid >> 6;
  const int lane = tid & 63;

  // ---- pass 1: count nonzeros per row ----
  for (int rl = 0; rl < 4; ++rl) {
    const int r = wave * 4 + rl;
    const float* wrow = W_res + (size_t)(row0 + r) * NN;
    unsigned cnt = 0;
    for (int c0 = 0; c0 < NN; c0 += 64) {
      const int c = c0 + lane;
      const float w = (c < NN) ? wrow[c] : 0.0f;
      cnt += (unsigned)__popcll(__ballot(w != 0.0f));
    }
    if (lane == 0) s_cnt[r] = cnt;
  }
  __syncthreads();
  if (tid == 0) {
    unsigned acc = 0;
    for (int r = 0; r < ROWS_PER_WG; ++r) { s_start[r] = acc; acc += s_cnt[r]; }
    s_start[ROWS_PER_WG] = acc;
  }
  __syncthreads();

  // ---- pass 2: ordered fill, packed {val, col} ----
  for (int rl = 0; rl < 4; ++rl) {
    const int r = wave * 4 + rl;
    const float* wrow = W_res + (size_t)(row0 + r) * NN;
    unsigned off = s_start[r];
    for (int c0 = 0; c0 < NN; c0 += 64) {
      const int c = c0 + lane;
      const float w = (c < NN) ? wrow[c] : 0.0f;
      const unsigned long long m = __ballot(w != 0.0f);
      if (w != 0.0f) {
        const unsigned pos = off + (unsigned)__popcll(m & ((1ULL << lane) - 1ULL));
        if (pos < MAX_NNZ) s_pk[pos] = make_float2(w, __uint_as_float((unsigned)c));
      }
      off += (unsigned)__popcll(m);
    }
  }

  for (int i = tid; i < NN; i += TPB) s_h[i] = 0.0f;   // h_0 = 0
  __syncthreads();

  const int r = tid >> 4;       // row within slice (0..15)
  const int l16 = tid & 15;     // lane within row-group
  const int myrow = row0 + r;
  const unsigned kbeg = s_start[r];
  const unsigned kend = s_start[r + 1];

  // fused poll+pull assignment: thread tid handles producer p (p==wg skipped:
  // own rows arrive via LDS short-circuit)
  const int p = (tid < NWG) ? (tid + wg) % NWG : 0;
  const int jrot = tid & 7;     // rotation to spread LDS write banks

  float dv = (l16 == 0) ? drive[myrow] : 0.0f;   // drive for t=0

  for (int t = 0; t < T_STEPS; ++t) {
    // ---- gather: 2-way unrolled, 2 LDS instrs per nnz ----
    float acc0 = 0.0f, acc1 = 0.0f;
    unsigned k = kbeg + (unsigned)l16;
    for (; k + 16 < kend; k += 32) {
      const float2 p0 = s_pk[k];
      const float2 p1 = s_pk[k + 16];
      acc0 += p0.x * s_h[__float_as_uint(p0.y)];
      acc1 += p1.x * s_h[__float_as_uint(p1.y)];
    }
    if (k < kend) { const float2 pk = s_pk[k]; acc0 += pk.x * s_h[__float_as_uint(pk.y)]; }
    float acc = acc0 + acc1;
    acc += __shfl_xor(acc, 1);
    acc += __shfl_xor(acc, 2);
    acc += __shfl_xor(acc, 4);
    acc += __shfl_xor(acc, 8);

    // prefetch next step's drive (1 cacheline per WG) to hide latency
    const float dv_next = (l16 == 0 && t + 1 < T_STEPS)
                              ? drive[(size_t)(t + 1) * NN + myrow] : 0.0f;

    const unsigned tgt = (unsigned)(t + 1);
    float hn = 0.0f;
    if (l16 == 0) {
      hn = LEAK * tanhf(acc + dv) + (1.0f - LEAK) * s_h[myrow];
      // self-flagging publish: ONE b64 WT agent store {tag, h}
      const unsigned long long pk =
          ((unsigned long long)tgt << 32) | (unsigned long long)__float_as_uint(hn);
      __hip_atomic_store(&pdata[(size_t)(t & 1) * NN + myrow], pk,
                         __ATOMIC_RELAXED, __HIP_MEMORY_SCOPE_AGENT);
      // plain cached store for out_kernel (read only after kernel end)
      states[(size_t)t * NN + myrow] = hn;
    }
    dv = dv_next;
    if (t == T_STEPS - 1) break;

    __syncthreads();     // B1: all gathers done — s_h free to overwrite

    if (l16 == 0) s_h[myrow] = hn;   // own rows: LDS short-circuit

    if (tid < NWG && p != wg) {
      const unsigned long long* src = pdata + (size_t)(t & 1) * NN + (size_t)p * 16;
      // 1) spin on ONE word only (poll volume == R9 tag level)
      unsigned long long v15;
      while ((unsigned)((v15 = __hip_atomic_load(&src[15], __ATOMIC_RELAXED,
                                                 __HIP_MEMORY_SCOPE_AGENT)) >> 32) < tgt)
        __builtin_amdgcn_s_sleep(1);
      asm volatile("" ::: "memory");
      // 2) burst-load remaining 15 words; validate embedded tags; rare retry
      unsigned long long v[15];
      for (;;) {
        bool all = true;
#pragma unroll
        for (int j = 0; j < 15; ++j) {
          v[j] = __hip_atomic_load(&src[j], __ATOMIC_RELAXED,
                                   __HIP_MEMORY_SCOPE_AGENT);
          all &= ((unsigned)(v[j] >> 32) >= tgt);
        }
        if (all) break;
        __builtin_amdgcn_s_sleep(1);
      }
      // 3) repack h pairs and write LDS as rotated b64s (R9 bank pattern)
      unsigned long long w[8];
#pragma unroll
      for (int j = 0; j < 7; ++j)
        w[j] = (v[2 * j] & 0xFFFFFFFFull) | (v[2 * j + 1] << 32);
      w[7] = (v[14] & 0xFFFFFFFFull) | (v15 << 32);
      unsigned long long* dst = (unsigned long long*)&s_h[p * 16];
#pragma unroll
      for (int jj = 0; jj < 8; ++jj) {
        const int j = (jj + jrot) & 7;
        dst[j] = w[j];
      }
    }
    __syncthreads();     // B2: s_h = h_{t+1} complete
  }
}

// ---------------------------------------------------------------------------
__global__ void out_kernel(const float* __restrict__ X, const float* __restrict__ states,
                           const float* __restrict__ WoT, float* __restrict__ out) {
  const int o = threadIdx.x & 31;
  const int tl = threadIdx.x >> 5;
  const int t = blockIdx.x * 8 + tl;
  float acc = 0.0f;
  const float* xrow = X + (size_t)t * N_IN;
#pragma unroll
  for (int k = 0; k < N_IN; ++k) acc += xrow[k] * WoT[k * N_OUT + o];
  const float* srow = states + (size_t)t * NN;
  for (int j = 0; j < NN; ++j) acc += srow[j] * WoT[(N_IN + j) * N_OUT + o];
  out[(size_t)t * N_OUT + o] = acc;
}

// ---------------------------------------------------------------------------
extern "C" void kernel_launch(void* const* d_in, const int* in_sizes, int n_in,
                              void* d_out, int out_size, void* d_ws, size_t ws_size,
                              hipStream_t stream) {
  const float* X     = (const float*)d_in[0];
  const float* y     = (const float*)d_in[1];
  const float* W_in  = (const float*)d_in[2];
  const float* W_res = (const float*)d_in[3];
  const float* W_fb  = (const float*)d_in[4];
  const float* W_out = (const float*)d_in[5];
  const float* b     = (const float*)d_in[6];
  float* out = (float*)d_out;

  // workspace layout (float offsets):
  //   drive : [2048][4000]        at 0            (8,192,000)
  //   states: [2048][4000]        at 8,192,000    (8,192,000)
  //   WoT   : [4032][32]          at 16,384,000   (129,024)
  //   pdata : [2][4000] u64       at 16,513,024   (16,000 floats; 8B-aligned)
  float* ws = (float*)d_ws;
  float* drive    = ws;
  float* states   = ws + 8192000;
  float* WoT      = ws + 16384000;
  unsigned long long* pdata = (unsigned long long*)(ws + 16513024);

  hipMemsetAsync(pdata, 0, 2 * NN * sizeof(unsigned long long), stream);
  drive_kernel<<<dim3(16, T_STEPS), TPB, 0, stream>>>(X, y, W_in, W_fb, b, drive);
  transpose_wout_kernel<<<(N_OUT * NEXT + TPB - 1) / TPB, TPB, 0, stream>>>(W_out, WoT);
  esn_scan_kernel<<<NWG, TPB, 0, stream>>>(W_res, drive, states, pdata);
  out_kernel<<<T_STEPS / 8, TPB, 0, stream>>>(X, states, WoT, out);
}

// Round 12
// 15401.091 us; speedup vs baseline: 1.3030x; 1.0506x over previous
//
#include <hip/hip_runtime.h>
#include <hip/hip_bf16.h>

#define T_STEPS 2048
#define NN 4000
#define N_IN 32
#define N_OUT 32
#define NEXT 4032          // N_IN + NN
#define NWG 250            // workgroups in persistent scan kernel
#define ROWS_PER_WG 16     // 250*16 = 4000
#define TPB 256
#define MAX_NNZ 7680       // per-WG LDS nnz capacity (mean 6400, sigma 76)
#define LEAK 0.99f
#define TAG_STRIDE 16      // u32s = 64B per tag line (own cacheline per WG)

// ---------------------------------------------------------------------------
// drive[t][n] = b + sum_k X[t][k]*W_in[n][k] + sum_k y[t][k]*W_fb[n][k]
// ---------------------------------------------------------------------------
__global__ void drive_kernel(const float* __restrict__ X, const float* __restrict__ y,
                             const float* __restrict__ W_in, const float* __restrict__ W_fb,
                             const float* __restrict__ b, float* __restrict__ drive) {
  __shared__ float s_x[N_IN];
  __shared__ float s_y[N_OUT];
  const int t = blockIdx.y;
  const int tid = threadIdx.x;
  if (tid < N_IN) s_x[tid] = X[t * N_IN + tid];
  else if (tid < N_IN + N_OUT) s_y[tid - N_IN] = y[t * N_OUT + (tid - N_IN)];
  __syncthreads();
  const int n = blockIdx.x * TPB + tid;
  if (n < NN) {
    float acc = b[0];
    const float* wi = W_in + (size_t)n * N_IN;
    const float* wf = W_fb + (size_t)n * N_OUT;
#pragma unroll
    for (int k = 0; k < N_IN; ++k) acc += s_x[k] * wi[k];
#pragma unroll
    for (int k = 0; k < N_OUT; ++k) acc += s_y[k] * wf[k];
    drive[(size_t)t * NN + n] = acc;
  }
}

// ---------------------------------------------------------------------------
__global__ void transpose_wout_kernel(const float* __restrict__ W_out, float* __restrict__ WoT) {
  const int idx = blockIdx.x * TPB + threadIdx.x;
  if (idx < N_OUT * NEXT) {
    const int o = idx / NEXT;
    const int k = idx % NEXT;
    WoT[k * N_OUT + o] = W_out[idx];
  }
}

// ---------------------------------------------------------------------------
// Persistent scan kernel. 250 WGs x 256 threads, 1 WG/CU.
// CSR slice of 16 rows packed {val,col} in LDS.
// R12 exchange = R9's single-tag detect (1 outstanding poll per thread —
// the only poll structure that doesn't congest the IF) MINUS the vmcnt(0)
// store-ack RTT, made safe by VALIDATED pulls:
//   producers: per-row b64 {tag=t+1, h} WT agent store into pdata[t&1]
//              (+ plain cached store to states[] for out_kernel);
//              tag[wg] stored by thread 0 right AFTER B1 — ordered after all
//              row-stores are ISSUED (not acked; no vmcnt, no fence).
//   consumers: hot-poll producer's tag line (single word, 1 outstanding);
//              then pull 16 {tag,h} words ONCE and validate embedded tags,
//              re-loading only stale words (rare: data had a flight-time
//              head start over tag+detect).
// Parity-2 overwrite safety (R10 proof): producer reaches step t+2's publish
// only after completing step t+1's pull, which needs every WG's t+1 publish,
// which needs their step-t pull complete. Max skew 1 step; t+1 uses the
// other parity slot. Tag monotonicity makes `>= tgt` validation sound.
// ---------------------------------------------------------------------------
__global__ __launch_bounds__(TPB, 1) void esn_scan_kernel(
    const float* __restrict__ W_res,
    const float* __restrict__ drive,
    float* __restrict__ states,
    unsigned* __restrict__ tags,               // [NWG][TAG_STRIDE]
    unsigned long long* __restrict__ pdata) {  // [2][NN] packed {tag,h}
  __shared__ float2 s_pk[MAX_NNZ];          // {val, col bits} : one b64 per nnz
  __shared__ __align__(16) float s_h[NN];
  __shared__ unsigned s_cnt[ROWS_PER_WG];
  __shared__ unsigned s_start[ROWS_PER_WG + 1];

  const int tid = threadIdx.x;
  const int wg = blockIdx.x;
  const int row0 = wg * ROWS_PER_WG;
  const int wave = tid >> 6;
  const int lane = tid & 63;

  // ---- pass 1: count nonzeros per row ----
  for (int rl = 0; rl < 4; ++rl) {
    const int r = wave * 4 + rl;
    const float* wrow = W_res + (size_t)(row0 + r) * NN;
    unsigned cnt = 0;
    for (int c0 = 0; c0 < NN; c0 += 64) {
      const int c = c0 + lane;
      const float w = (c < NN) ? wrow[c] : 0.0f;
      cnt += (unsigned)__popcll(__ballot(w != 0.0f));
    }
    if (lane == 0) s_cnt[r] = cnt;
  }
  __syncthreads();
  if (tid == 0) {
    unsigned acc = 0;
    for (int r = 0; r < ROWS_PER_WG; ++r) { s_start[r] = acc; acc += s_cnt[r]; }
    s_start[ROWS_PER_WG] = acc;
  }
  __syncthreads();

  // ---- pass 2: ordered fill, packed {val, col} ----
  for (int rl = 0; rl < 4; ++rl) {
    const int r = wave * 4 + rl;
    const float* wrow = W_res + (size_t)(row0 + r) * NN;
    unsigned off = s_start[r];
    for (int c0 = 0; c0 < NN; c0 += 64) {
      const int c = c0 + lane;
      const float w = (c < NN) ? wrow[c] : 0.0f;
      const unsigned long long m = __ballot(w != 0.0f);
      if (w != 0.0f) {
        const unsigned pos = off + (unsigned)__popcll(m & ((1ULL << lane) - 1ULL));
        if (pos < MAX_NNZ) s_pk[pos] = make_float2(w, __uint_as_float((unsigned)c));
      }
      off += (unsigned)__popcll(m);
    }
  }

  for (int i = tid; i < NN; i += TPB) s_h[i] = 0.0f;   // h_0 = 0
  __syncthreads();

  const int r = tid >> 4;       // row within slice (0..15)
  const int l16 = tid & 15;     // lane within row-group
  const int myrow = row0 + r;
  const unsigned kbeg = s_start[r];
  const unsigned kend = s_start[r + 1];

  // fused poll+pull assignment: thread tid handles producer p (p==wg skipped:
  // own rows arrive via LDS short-circuit)
  const int p = (tid < NWG) ? (tid + wg) % NWG : 0;

  float dv = (l16 == 0) ? drive[myrow] : 0.0f;   // drive for t=0

  for (int t = 0; t < T_STEPS; ++t) {
    // ---- gather: 2-way unrolled, 2 LDS instrs per nnz ----
    float acc0 = 0.0f, acc1 = 0.0f;
    unsigned k = kbeg + (unsigned)l16;
    for (; k + 16 < kend; k += 32) {
      const float2 p0 = s_pk[k];
      const float2 p1 = s_pk[k + 16];
      acc0 += p0.x * s_h[__float_as_uint(p0.y)];
      acc1 += p1.x * s_h[__float_as_uint(p1.y)];
    }
    if (k < kend) { const float2 pk = s_pk[k]; acc0 += pk.x * s_h[__float_as_uint(pk.y)]; }
    float acc = acc0 + acc1;
    acc += __shfl_xor(acc, 1);
    acc += __shfl_xor(acc, 2);
    acc += __shfl_xor(acc, 4);
    acc += __shfl_xor(acc, 8);

    // prefetch next step's drive (1 cacheline per WG) to hide latency
    const float dv_next = (l16 == 0 && t + 1 < T_STEPS)
                              ? drive[(size_t)(t + 1) * NN + myrow] : 0.0f;

    const unsigned tgt = (unsigned)(t + 1);
    float hn = 0.0f;
    if (l16 == 0) {
      hn = LEAK * tanhf(acc + dv) + (1.0f - LEAK) * s_h[myrow];
      // self-validating publish: ONE b64 WT agent store {tag, h}
      const unsigned long long pk =
          ((unsigned long long)tgt << 32) | (unsigned long long)__float_as_uint(hn);
      __hip_atomic_store(&pdata[(size_t)(t & 1) * NN + myrow], pk,
                         __ATOMIC_RELAXED, __HIP_MEMORY_SCOPE_AGENT);
      // plain cached store for out_kernel (read only after kernel end)
      states[(size_t)t * NN + myrow] = hn;
    }
    dv = dv_next;
    if (t == T_STEPS - 1) break;

    __syncthreads();   // B1: all publishes ISSUED + all gathers done (s_h WAR)

    // tag after B1: ordered after issue of all 16 row-stores; no ack needed —
    // consumers validate embedded tags on pull.
    if (tid == 0) {
      __hip_atomic_store(&tags[wg * TAG_STRIDE], tgt, __ATOMIC_RELAXED,
                         __HIP_MEMORY_SCOPE_AGENT);
    }

    if (l16 == 0) s_h[myrow] = hn;   // own rows: LDS short-circuit

    if (tid < NWG && p != wg) {
      // detect: hot-poll ONE tag line, exactly 1 outstanding request
      while (__hip_atomic_load(&tags[p * TAG_STRIDE], __ATOMIC_RELAXED,
                               __HIP_MEMORY_SCOPE_AGENT) < tgt) {}
      // pull 16 {tag,h} words once; validate; re-load only stale words
      const unsigned long long* src = pdata + (size_t)(t & 1) * NN + (size_t)p * 16;
      unsigned long long v[16];
#pragma unroll
      for (int j = 0; j < 16; ++j)
        v[j] = __hip_atomic_load(&src[j], __ATOMIC_RELAXED,
                                 __HIP_MEMORY_SCOPE_AGENT);
      for (;;) {
        bool any_stale = false;
#pragma unroll
        for (int j = 0; j < 16; ++j) {
          if ((unsigned)(v[j] >> 32) < tgt) {
            v[j] = __hip_atomic_load(&src[j], __ATOMIC_RELAXED,
                                     __HIP_MEMORY_SCOPE_AGENT);
            any_stale |= ((unsigned)(v[j] >> 32) < tgt);
          }
        }
        if (!any_stale) break;
        __builtin_amdgcn_s_sleep(1);
      }
#pragma unroll
      for (int j = 0; j < 16; ++j)
        s_h[p * 16 + j] = __uint_as_float((unsigned)v[j]);
    }
    __syncthreads();   // B2: s_h = h_{t+1} complete
  }
}

// ---------------------------------------------------------------------------
__global__ void out_kernel(const float* __restrict__ X, const float* __restrict__ states,
                           const float* __restrict__ WoT, float* __restrict__ out) {
  const int o = threadIdx.x & 31;
  const int tl = threadIdx.x >> 5;
  const int t = blockIdx.x * 8 + tl;
  float acc = 0.0f;
  const float* xrow = X + (size_t)t * N_IN;
#pragma unroll
  for (int k = 0; k < N_IN; ++k) acc += xrow[k] * WoT[k * N_OUT + o];
  const float* srow = states + (size_t)t * NN;
  for (int j = 0; j < NN; ++j) acc += srow[j] * WoT[(N_IN + j) * N_OUT + o];
  out[(size_t)t * N_OUT + o] = acc;
}

// ---------------------------------------------------------------------------
extern "C" void kernel_launch(void* const* d_in, const int* in_sizes, int n_in,
                              void* d_out, int out_size, void* d_ws, size_t ws_size,
                              hipStream_t stream) {
  const float* X     = (const float*)d_in[0];
  const float* y     = (const float*)d_in[1];
  const float* W_in  = (const float*)d_in[2];
  const float* W_res = (const float*)d_in[3];
  const float* W_fb  = (const float*)d_in[4];
  const float* W_out = (const float*)d_in[5];
  const float* b     = (const float*)d_in[6];
  float* out = (float*)d_out;

  // workspace layout (float offsets):
  //   drive : [2048][4000]        at 0            (8,192,000)
  //   states: [2048][4000]        at 8,192,000    (8,192,000)
  //   WoT   : [4032][32]          at 16,384,000   (129,024)
  //   tags  : [250][16] u32       at 16,513,024   (4,000 -> pad 4,096)
  //   pdata : [2][4000] u64       at 16,517,120   (16,000 floats; 8B-aligned)
  float* ws = (float*)d_ws;
  float* drive    = ws;
  float* states   = ws + 8192000;
  float* WoT      = ws + 16384000;
  unsigned* tags  = (unsigned*)(ws + 16513024);
  unsigned long long* pdata = (unsigned long long*)(ws + 16517120);

  hipMemsetAsync(tags, 0, 4096 * sizeof(unsigned), stream);
  hipMemsetAsync(pdata, 0, 2 * NN * sizeof(unsigned long long), stream);
  drive_kernel<<<dim3(16, T_STEPS), TPB, 0, stream>>>(X, y, W_in, W_fb, b, drive);
  transpose_wout_kernel<<<(N_OUT * NEXT + TPB - 1) / TPB, TPB, 0, stream>>>(W_out, WoT);
  esn_scan_kernel<<<NWG, TPB, 0, stream>>>(W_res, drive, states, tags, pdata);
  out_kernel<<<T_STEPS / 8, TPB, 0, stream>>>(X, states, WoT, out);
}